// Round 5
// baseline (221.603 us; speedup 1.0000x reference)
//
#include <hip/hip_runtime.h>

// Problem constants (match reference)
#define V_ 100000
#define D_ 256
#define M_ 4096
#define C_ 4096
#define L_ 32
#define ROWS_MEMS (M_ + 1)          // 4097 rows in mems_enc (mems + xs_emb)
#define NTASK (1 + M_ + 1 + C_)     // 8194 encode row-tasks
#define NBLK 1025                   // 4100 waves; each wave: row g and row g+4100
#define HALF (NBLK * 4)             // 4100

__device__ __forceinline__ float wave_allreduce_sum(float v) {
    #pragma unroll
    for (int off = 32; off >= 1; off >>= 1) v += __shfl_xor(v, off, 64);
    return v;
}

// ---------------------------------------------------------------------------
// Fused encode + attention + weighted accumulation, latency-optimized:
//  - wave-uniform scalar loads for tokens/freqs (s_load path, no bpermute on
//    the gather address chain)
//  - 2 rows per wave (64 independent float4 gathers in flight)
//  - __launch_bounds__(256,4): up to 128 VGPR for deep load pipelining
// Row A (rt = g in 0..4099): xs/mems rows fuse exp(cos) + LDS/global
// accumulate (cos in [-1,1] -> exp without max-subtraction is safe);
// rt 4097..4099 are ys/cands -> straight to out_ys.
// Row B (rt = g+4100): always a cands row -> straight to out_ys.
// ---------------------------------------------------------------------------
__global__ __launch_bounds__(256, 4) void encode_fused(
    const int* __restrict__ xs, const int* __restrict__ mems,
    const int* __restrict__ ys, const int* __restrict__ cands,
    const float* __restrict__ lt, const float* __restrict__ freqs,
    float* __restrict__ lhs_raw,   // [256], zeroed: sum_i e_i * row_i
    float* __restrict__ gsum,      // [1],  zeroed: sum_i e_i
    float* __restrict__ out_ys)    // d_out second half: [4097, 256]
{
    __shared__ float s_xf[D_];     // xs embedding fragment
    __shared__ float s_an2;        // ||xs||^2
    __shared__ float s_lred[D_];   // block partial of sum e*row
    __shared__ float s_ered;       // block partial of sum e

    const int wave = threadIdx.x >> 6;
    const int lane = threadIdx.x & 63;
    const int d0 = lane * 4;               // 64 lanes x 4 floats = 256
    const int g = blockIdx.x * 4 + wave;   // 0..4099

    s_lred[threadIdx.x] = 0.f;
    if (threadIdx.x == 0) s_ered = 0.f;

    // wave 0: xs fragment once per block (32 L1/L2-hot rows, uniform tokens)
    if (wave == 0) {
        float s2 = 0.f;
        #pragma unroll
        for (int l = 0; l < L_; ++l) { const float w = freqs[xs[l]]; s2 += w * w; }
        const float inv = 1.0f / sqrtf(s2);
        float4 xf = make_float4(0.f, 0.f, 0.f, 0.f);
        #pragma unroll
        for (int l = 0; l < L_; ++l) {
            const int t = xs[l];
            const float wl = freqs[t] * inv;
            const float4 v = *reinterpret_cast<const float4*>(lt + (size_t)t * D_ + d0);
            xf.x += wl * v.x; xf.y += wl * v.y; xf.z += wl * v.z; xf.w += wl * v.w;
        }
        *reinterpret_cast<float4*>(&s_xf[d0]) = xf;
        const float an2 = wave_allreduce_sum(xf.x*xf.x + xf.y*xf.y + xf.z*xf.z + xf.w*xf.w);
        if (lane == 0) s_an2 = an2;
    }
    __syncthreads();

    // ---- resolve row A (rt in 0..4099)
    const int rtA = g;
    const int* tpA; float* dstA = nullptr; int aiA = -1;
    if (rtA == 0) {
        tpA = xs; aiA = M_;
    } else if (rtA <= M_) {
        tpA = mems + (size_t)(rtA - 1) * L_; aiA = rtA - 1;
    } else if (rtA == M_ + 1) {
        tpA = ys; dstA = out_ys;
    } else {
        const int c = rtA - (M_ + 2);
        tpA = cands + (size_t)c * L_;
        dstA = out_ys + (size_t)(c + 1) * D_;
    }

    // ---- resolve row B (rt = g+4100 in 4100..8199; valid ones are all cands)
    const int rtB = g + HALF;
    const bool hasB = (rtB < NTASK);
    const int cB = hasB ? (rtB - (M_ + 2)) : 0;
    const int* tpB = cands + (size_t)cB * L_;
    float* dstB = out_ys + (size_t)(cB + 1) * D_;

    // ---- pass 1: weight norms (uniform scalar loads, scalar-cache hot after)
    float s2A = 0.f, s2B = 0.f;
    #pragma unroll
    for (int l = 0; l < L_; ++l) {
        const float wa = freqs[tpA[l]]; s2A += wa * wa;
        const float wb = freqs[tpB[l]]; s2B += wb * wb;
    }
    const float invA = 1.0f / sqrtf(s2A);
    const float invB = 1.0f / sqrtf(s2B);

    // ---- pass 2: interleaved gather-accumulate, 64 independent float4 loads
    float4 accA = make_float4(0.f, 0.f, 0.f, 0.f);
    float4 accB = make_float4(0.f, 0.f, 0.f, 0.f);
    #pragma unroll
    for (int l = 0; l < L_; ++l) {
        const int ta = tpA[l];
        const int tb = tpB[l];
        const float wa = freqs[ta] * invA;
        const float wb = freqs[tb] * invB;
        const float4 va = *reinterpret_cast<const float4*>(lt + (size_t)ta * D_ + d0);
        const float4 vb = *reinterpret_cast<const float4*>(lt + (size_t)tb * D_ + d0);
        accA.x += wa * va.x; accA.y += wa * va.y; accA.z += wa * va.z; accA.w += wa * va.w;
        accB.x += wb * vb.x; accB.y += wb * vb.y; accB.z += wb * vb.z; accB.w += wb * vb.w;
    }

    // ---- row A epilogue: attention fuse or direct store
    if (aiA >= 0) {
        const float4 xf = *reinterpret_cast<const float4*>(&s_xf[d0]);
        const float d = wave_allreduce_sum(accA.x*xf.x + accA.y*xf.y + accA.z*xf.z + accA.w*xf.w);
        const float q = wave_allreduce_sum(accA.x*accA.x + accA.y*accA.y + accA.z*accA.z + accA.w*accA.w);
        const float an = fmaxf(sqrtf(s_an2), 1e-8f);
        const float bn = fmaxf(sqrtf(q),  1e-8f);
        const float e = expf(d / (an * bn));     // same value on all lanes
        atomicAdd(&s_lred[d0 + 0], e * accA.x);  // LDS atomics: 4-wave combine
        atomicAdd(&s_lred[d0 + 1], e * accA.y);
        atomicAdd(&s_lred[d0 + 2], e * accA.z);
        atomicAdd(&s_lred[d0 + 3], e * accA.w);
        if (lane == 0) atomicAdd(&s_ered, e);
    } else {
        *reinterpret_cast<float4*>(dstA + d0) = accA;
    }
    // ---- row B epilogue: always a cands row
    if (hasB) *reinterpret_cast<float4*>(dstB + d0) = accB;

    // ---- block combine -> global accumulators (every block has att rows)
    __syncthreads();
    atomicAdd(&lhs_raw[threadIdx.x], s_lred[threadIdx.x]);
    if (threadIdx.x == 0) atomicAdd(gsum, s_ered);
}

// ---------------------------------------------------------------------------
// K2: normalize lhs by the softmax denominator and tile into out_xs rows.
// ---------------------------------------------------------------------------
__global__ __launch_bounds__(256) void finalize_tile(
    const float* __restrict__ lhs_raw, const float* __restrict__ gsum,
    float* __restrict__ out_xs)
{
    const float val = lhs_raw[threadIdx.x] / gsum[0];
    for (int r = blockIdx.x; r < ROWS_MEMS; r += gridDim.x)
        out_xs[(size_t)r * D_ + threadIdx.x] = val;
}

extern "C" void kernel_launch(void* const* d_in, const int* in_sizes, int n_in,
                              void* d_out, int out_size, void* d_ws, size_t ws_size,
                              hipStream_t stream) {
    const int*   xs    = (const int*)d_in[0];
    const int*   mems  = (const int*)d_in[1];
    const int*   ys    = (const int*)d_in[2];
    const int*   cands = (const int*)d_in[3];
    const float* lt    = (const float*)d_in[4];
    const float* freqs = (const float*)d_in[5];

    float* out    = (float*)d_out;
    float* out_xs = out;                                   // [4097, 256]
    float* out_ys = out + (size_t)ROWS_MEMS * D_;          // [4097, 256]

    // ws layout (floats): lhs_raw[256] | gsum[1]
    float* lhs_raw = (float*)d_ws;
    float* gsum    = lhs_raw + D_;

    hipMemsetAsync(lhs_raw, 0, (D_ + 1) * sizeof(float), stream);

    encode_fused<<<NBLK, 256, 0, stream>>>(xs, mems, ys, cands, lt, freqs,
                                           lhs_raw, gsum, out_ys);
    finalize_tile<<<1024, 256, 0, stream>>>(lhs_raw, gsum, out_xs);
}

// Round 7
// 191.076 us; speedup vs baseline: 1.1598x; 1.1598x over previous
//
#include <hip/hip_runtime.h>

// Problem constants (match reference)
#define V_ 100000
#define D_ 256
#define M_ 4096
#define C_ 4096
#define L_ 32
#define ROWS_MEMS (M_ + 1)          // 4097 rows in mems_enc (mems + xs_emb)
#define NTASK (1 + M_ + 1 + C_)     // 8194 encode row-tasks
#define NBLK 1025                   // 4100 waves; wave g does rows g and g+4100
#define HALF (NBLK * 4)             // 4100

__device__ __forceinline__ float wave_allreduce_sum(float v) {
    #pragma unroll
    for (int off = 32; off >= 1; off >>= 1) v += __shfl_xor(v, off, 64);
    return v;
}

// butterfly within each 32-lane half: every lane gets its half's sum
__device__ __forceinline__ float half_allreduce_sum(float v) {
    #pragma unroll
    for (int off = 16; off >= 1; off >>= 1) v += __shfl_xor(v, off, 64);
    return v;
}

// ---------------------------------------------------------------------------
// Fused encode + attention + weighted accumulation. 2 rows per wave:
// row-A tokens live in lanes 0..31, row-B tokens in lanes 32..63 (1 int +
// 1 float of register state per lane regardless of row count). The gather
// loop issues 64 independent float4 loads per wave — 2x the in-flight depth
// of round 4 — with no scalar-path register blowup (round-5's spill bug).
//   Row A (g in 0..4099): rows 0..4096 fuse exp(cos) + LDS/global accumulate
//   (cos in [-1,1] -> exp without max-subtraction is safe); 4097=ys,
//   4098/4099 = cands 0/1 -> straight to out_ys.
//   Row B (g+4100): always a cands row -> straight to out_ys.
// ---------------------------------------------------------------------------
__global__ __launch_bounds__(256) void encode_fused(
    const int* __restrict__ xs, const int* __restrict__ mems,
    const int* __restrict__ ys, const int* __restrict__ cands,
    const float* __restrict__ lt, const float* __restrict__ freqs,
    float* __restrict__ lhs_raw,   // [256], zeroed: sum_i e_i * row_i
    float* __restrict__ gsum,      // [1],  zeroed: sum_i e_i
    float* __restrict__ out_ys)    // d_out second half: [4097, 256]
{
    __shared__ float s_xf[D_];     // xs embedding fragment
    __shared__ float s_lred[D_];   // block partial of sum e*row
    __shared__ float s_an2, s_ered;

    const int wave = threadIdx.x >> 6;
    const int lane = threadIdx.x & 63;
    const int d0 = lane * 4;               // 64 lanes x 4 floats = 256
    const int g = blockIdx.x * 4 + wave;   // 0..4099

    s_lred[threadIdx.x] = 0.f;
    if (threadIdx.x == 0) s_ered = 0.f;

    // wave 0: xs fragment once per block (32 L1/L2-hot rows; every block
    // carries at least one att row, so always compute it)
    if (wave == 0) {
        int txs = 0; float wxs = 0.f;
        if (lane < L_) { txs = xs[lane]; wxs = freqs[txs]; }
        const float sx2 = wave_allreduce_sum(wxs * wxs);
        const float wnx = wxs / sqrtf(sx2);
        float4 xf = make_float4(0.f, 0.f, 0.f, 0.f);
        #pragma unroll
        for (int l = 0; l < L_; ++l) {
            const int t = __shfl(txs, l, 64);
            const float wl = __shfl(wnx, l, 64);
            const float4 v = *reinterpret_cast<const float4*>(lt + (size_t)t * D_ + d0);
            xf.x += wl * v.x; xf.y += wl * v.y; xf.z += wl * v.z; xf.w += wl * v.w;
        }
        *reinterpret_cast<float4*>(&s_xf[d0]) = xf;
        const float an2 = wave_allreduce_sum(xf.x*xf.x + xf.y*xf.y + xf.z*xf.z + xf.w*xf.w);
        if (lane == 0) s_an2 = an2;
    }
    __syncthreads();

    // ---- resolve row A (rt in 0..4099)
    const int rtA = g;
    const int* tpA; float* dstA = nullptr; int aiA = -1;
    if (rtA == 0) {
        tpA = xs; aiA = M_;
    } else if (rtA <= M_) {
        tpA = mems + (size_t)(rtA - 1) * L_; aiA = rtA - 1;
    } else if (rtA == M_ + 1) {
        tpA = ys; dstA = out_ys;
    } else {
        const int c = rtA - (M_ + 2);
        tpA = cands + (size_t)c * L_;
        dstA = out_ys + (size_t)(c + 1) * D_;
    }

    // ---- resolve row B (rt = g+4100; valid ones are all cands rows)
    const int rtB = g + HALF;
    const bool hasB = (rtB < NTASK);
    const int cB = hasB ? (rtB - (M_ + 2)) : 0;
    const int* tpB = cands + (size_t)cB * L_;
    float* dstB = out_ys + (size_t)(cB + 1) * D_;

    // tokens: lanes 0..31 = row A, lanes 32..63 = row B
    const int tok = (lane < 32) ? tpA[lane] : tpB[lane - 32];
    const float w = freqs[tok];
    const float s2 = half_allreduce_sum(w * w);   // per-half norm
    const float wn = w / sqrtf(s2);               // freqs > 0 -> s2 > 0

    // ---- gather loop: 64 independent float4 loads per wave
    float4 accA = make_float4(0.f, 0.f, 0.f, 0.f);
    float4 accB = make_float4(0.f, 0.f, 0.f, 0.f);
    #pragma unroll
    for (int l = 0; l < L_; ++l) {
        const int   ta = __shfl(tok, l, 64);
        const int   tb = __shfl(tok, 32 + l, 64);
        const float wa = __shfl(wn, l, 64);
        const float wb = __shfl(wn, 32 + l, 64);
        const float4 va = *reinterpret_cast<const float4*>(lt + (size_t)ta * D_ + d0);
        const float4 vb = *reinterpret_cast<const float4*>(lt + (size_t)tb * D_ + d0);
        accA.x += wa * va.x; accA.y += wa * va.y; accA.z += wa * va.z; accA.w += wa * va.w;
        accB.x += wb * vb.x; accB.y += wb * vb.y; accB.z += wb * vb.z; accB.w += wb * vb.w;
    }

    // ---- row A epilogue: attention fuse or direct store
    if (aiA >= 0) {
        const float4 xf = *reinterpret_cast<const float4*>(&s_xf[d0]);
        const float d = wave_allreduce_sum(accA.x*xf.x + accA.y*xf.y + accA.z*xf.z + accA.w*xf.w);
        const float q = wave_allreduce_sum(accA.x*accA.x + accA.y*accA.y + accA.z*accA.z + accA.w*accA.w);
        const float an = fmaxf(sqrtf(s_an2), 1e-8f);
        const float bn = fmaxf(sqrtf(q),  1e-8f);
        const float e = expf(d / (an * bn));     // same value on all lanes
        atomicAdd(&s_lred[d0 + 0], e * accA.x);  // LDS atomics: 4-wave combine
        atomicAdd(&s_lred[d0 + 1], e * accA.y);
        atomicAdd(&s_lred[d0 + 2], e * accA.z);
        atomicAdd(&s_lred[d0 + 3], e * accA.w);
        if (lane == 0) atomicAdd(&s_ered, e);
    } else {
        *reinterpret_cast<float4*>(dstA + d0) = accA;
    }
    // ---- row B epilogue: always a cands row
    if (hasB) *reinterpret_cast<float4*>(dstB + d0) = accB;

    // ---- block combine -> global accumulators
    __syncthreads();
    atomicAdd(&lhs_raw[threadIdx.x], s_lred[threadIdx.x]);
    if (threadIdx.x == 0) atomicAdd(gsum, s_ered);
}

// ---------------------------------------------------------------------------
// K2: normalize lhs by the softmax denominator and tile into out_xs rows.
// ---------------------------------------------------------------------------
__global__ __launch_bounds__(256) void finalize_tile(
    const float* __restrict__ lhs_raw, const float* __restrict__ gsum,
    float* __restrict__ out_xs)
{
    const float val = lhs_raw[threadIdx.x] / gsum[0];
    for (int r = blockIdx.x; r < ROWS_MEMS; r += gridDim.x)
        out_xs[(size_t)r * D_ + threadIdx.x] = val;
}

extern "C" void kernel_launch(void* const* d_in, const int* in_sizes, int n_in,
                              void* d_out, int out_size, void* d_ws, size_t ws_size,
                              hipStream_t stream) {
    const int*   xs    = (const int*)d_in[0];
    const int*   mems  = (const int*)d_in[1];
    const int*   ys    = (const int*)d_in[2];
    const int*   cands = (const int*)d_in[3];
    const float* lt    = (const float*)d_in[4];
    const float* freqs = (const float*)d_in[5];

    float* out    = (float*)d_out;
    float* out_xs = out;                                   // [4097, 256]
    float* out_ys = out + (size_t)ROWS_MEMS * D_;          // [4097, 256]

    // ws layout (floats): lhs_raw[256] | gsum[1]
    float* lhs_raw = (float*)d_ws;
    float* gsum    = lhs_raw + D_;

    hipMemsetAsync(lhs_raw, 0, (D_ + 1) * sizeof(float), stream);

    encode_fused<<<NBLK, 256, 0, stream>>>(xs, mems, ys, cands, lt, freqs,
                                           lhs_raw, gsum, out_ys);
    finalize_tile<<<1024, 256, 0, stream>>>(lhs_raw, gsum, out_xs);
}